// Round 10
// baseline (273.585 us; speedup 1.0000x reference)
//
#include <hip/hip_runtime.h>
#include <cstddef>
#include <cstdint>

constexpr int NN = 50000;          // nodes
constexpr int NE = 800000;         // edges (no self loops)
constexpr int ET = NE + NN;        // edges + self loops
constexpr int NB = 50;             // graphs
constexpr int SCAN_B = 1024;
constexpr int NBLK = (NN + SCAN_B - 1) / SCAN_B;   // 49
constexpr int NPB_F = 32;                          // nodes/block, front node branch (R21)
constexpr int NPB_T = 8;                           // nodes/block, transform (R12-proven)
constexpr int NTB_F = (NN + NPB_F - 1) / NPB_F;    // front node blocks (1563)
constexpr int MLPB = (ET + 1023) / 1024;           // edge-mlp blocks (4 edges/thread)
constexpr int MRKB  = (ET + 255) / 256;            // mark1 edge-scan blocks (256 thr)

typedef float v2f __attribute__((ext_vector_type(2)));

__device__ __forceinline__ float eluf(float x) { return x > 0.f ? x : expm1f(x); }

// round-to-nearest-even fp32 -> bf16 (as ushort)
__device__ __forceinline__ unsigned short f2bf(float f) {
    unsigned int u = __float_as_uint(f);
    unsigned int r = (u + 0x7fffu + ((u >> 16) & 1u)) >> 16;
    return (unsigned short)r;
}

// Interleaved 4-node {vs,vd} reduction over 64 lanes (R14-proven).
template <int NPB, typename NodeOf>
__device__ __forceinline__ void alpha_reduce_store(const float* acc, float as_t, float ad_t,
                                                   int lane, int head, NodeOf nodeOf,
                                                   float* __restrict__ asrc,
                                                   float* __restrict__ adst) {
    #pragma unroll
    for (int g = 0; g < NPB; g += 4) {
        float x0, x1, x2, x3;
        {
            float vs, vd;
            vs = acc[g + 0] * as_t; vd = acc[g + 0] * ad_t;
            x0 = ((lane & 1) ? vd : vs) + __shfl_xor((lane & 1) ? vs : vd, 1);
            vs = acc[g + 1] * as_t; vd = acc[g + 1] * ad_t;
            x1 = ((lane & 1) ? vd : vs) + __shfl_xor((lane & 1) ? vs : vd, 1);
            vs = acc[g + 2] * as_t; vd = acc[g + 2] * ad_t;
            x2 = ((lane & 1) ? vd : vs) + __shfl_xor((lane & 1) ? vs : vd, 1);
            vs = acc[g + 3] * as_t; vd = acc[g + 3] * ad_t;
            x3 = ((lane & 1) ? vd : vs) + __shfl_xor((lane & 1) ? vs : vd, 1);
        }
        float y0 = ((lane & 2) ? x1 : x0) + __shfl_xor((lane & 2) ? x0 : x1, 2);
        float y1 = ((lane & 2) ? x3 : x2) + __shfl_xor((lane & 2) ? x2 : x3, 2);
        float z  = ((lane & 4) ? y1 : y0) + __shfl_xor((lane & 4) ? y0 : y1, 4);
        z += __shfl_xor(z, 8);
        z += __shfl_xor(z, 16);
        z += __shfl_xor(z, 32);
        if (lane < 8) {
            int node = nodeOf(g + (lane >> 1));
            if (lane & 1) adst[node * 4 + head] = z;
            else          asrc[node * 4 + head] = z;
        }
    }
}

// ---------------- per-node aggregation body (R9 2-deep two-half structure) ----------------
// WRITE_LDS: also deposit the elu'd output row into xs_row (for the fused readout).
template <bool WRITE_LDS>
__device__ __forceinline__ void aggregate_one_node(
        int widx, int lane,
        const unsigned short* __restrict__ hb,
        const float* __restrict__ asrc, const float* __restrict__ adst,
        const int2* __restrict__ csr, const float* __restrict__ ce_l,
        const float* __restrict__ bias_l, const int* __restrict__ row_ptr,
        float* __restrict__ xi, int residual, float* xs_row) {
    int half = lane >> 5;
    int li = lane & 31;        // channels li*8 .. li*8+7
    int head = li >> 3;        // head
    int start = row_ptr[widx], end = row_ptr[widx + 1];
    float adw = adst[widx * 4 + head];
    float ceh = ce_l[head];
    const uint4* hbv = (const uint4*)hb;

    v2f acc2[4];
    #pragma unroll
    for (int r = 0; r < 4; ++r) { acc2[r].x = 0.f; acc2[r].y = 0.f; }
    float psum = 0.f;

    #define PROC(EI)                                                                  \
        {                                                                             \
            const int2 se = csr[EI];                                                  \
            int s = se.x;                                                             \
            float w = __int_as_float(se.y);                                           \
            const uint4 q = hbv[(unsigned)s * 32u + (unsigned)li];                    \
            float v = asrc[s * 4 + head] + adw + w * ceh;                             \
            v = v > 0.f ? v : 0.2f * v;                                               \
            float p = __expf(v);                                                      \
            psum += p;                                                                \
            v2f pv; pv.x = p; pv.y = p;                                               \
            v2f h0; h0.x = __uint_as_float(q.x << 16); h0.y = __uint_as_float(q.x & 0xffff0000u); \
            v2f h1; h1.x = __uint_as_float(q.y << 16); h1.y = __uint_as_float(q.y & 0xffff0000u); \
            v2f h2; h2.x = __uint_as_float(q.z << 16); h2.y = __uint_as_float(q.z & 0xffff0000u); \
            v2f h3; h3.x = __uint_as_float(q.w << 16); h3.y = __uint_as_float(q.w & 0xffff0000u); \
            acc2[0] += pv * h0;                                                       \
            acc2[1] += pv * h1;                                                       \
            acc2[2] += pv * h2;                                                       \
            acc2[3] += pv * h3;                                                       \
        }

    int ei = start + half;
    for (; ei + 2 < end; ei += 4) {   // 2 edges per half per iter -> 2 gathers in flight
        PROC(ei);
        PROC(ei + 2);
    }
    if (ei < end) PROC(ei);
    #undef PROC

    float acc[8];
    acc[0] = acc2[0].x; acc[1] = acc2[0].y; acc[2] = acc2[1].x; acc[3] = acc2[1].y;
    acc[4] = acc2[2].x; acc[5] = acc2[2].y; acc[6] = acc2[3].x; acc[7] = acc2[3].y;

    psum += __shfl_xor(psum, 32);
    #pragma unroll
    for (int r = 0; r < 8; ++r) acc[r] += __shfl_xor(acc[r], 32);

    float inv = 1.f / (psum + 1e-16f);
    #pragma unroll
    for (int r = 0; r < 8; ++r) acc[r] *= inv;

    #pragma unroll
    for (int r = 0; r < 8; ++r) {
        acc[r] += __shfl_xor(acc[r], 8);
        acc[r] += __shfl_xor(acc[r], 16);
        acc[r] *= 0.25f;
    }

    if (lane < 8) {
        int c0 = lane * 8;
        const float4 b0 = *(const float4*)(bias_l + c0);
        const float4 b1 = *(const float4*)(bias_l + c0 + 4);
        float4 v0, v1;
        v0.x = acc[0] + b0.x; v0.y = acc[1] + b0.y; v0.z = acc[2] + b0.z; v0.w = acc[3] + b0.w;
        v1.x = acc[4] + b1.x; v1.y = acc[5] + b1.y; v1.z = acc[6] + b1.z; v1.w = acc[7] + b1.w;
        float* xo = xi + (size_t)widx * 64 + c0;
        if (residual) {
            const float4 p0 = *(const float4*)xo;
            const float4 p1 = *(const float4*)(xo + 4);
            v0.x += p0.x; v0.y += p0.y; v0.z += p0.z; v0.w += p0.w;
            v1.x += p1.x; v1.y += p1.y; v1.z += p1.z; v1.w += p1.w;
        }
        v0.x = eluf(v0.x); v0.y = eluf(v0.y); v0.z = eluf(v0.z); v0.w = eluf(v0.w);
        v1.x = eluf(v1.x); v1.y = eluf(v1.y); v1.z = eluf(v1.z); v1.w = eluf(v1.w);
        *(float4*)xo = v0;
        *(float4*)(xo + 4) = v1;
        if (WRITE_LDS) {
            *(float4*)(xs_row + c0) = v0;
            *(float4*)(xs_row + c0 + 4) = v1;
        }
    }
}

// ---------------- front dispatch (R21 order): edge-MLP+hist | mark1 flags | node_transform ----
// Long-serial-chain MLP blocks first; numerous short node blocks pack the tail.
__global__ void front_kernel(const float* __restrict__ xin, const float* __restrict__ W,
                             const float* __restrict__ a_s, const float* __restrict__ a_d,
                             unsigned short* __restrict__ hb, float* __restrict__ asrc,
                             float* __restrict__ adst,
                             const float* __restrict__ ea,
                             const float* __restrict__ w1, const float* __restrict__ b1,
                             const float* __restrict__ w2, const float* __restrict__ b2,
                             const int* __restrict__ ei_src, const int* __restrict__ ei_dst,
                             int* __restrict__ deg,
                             int2* __restrict__ ewp, float* __restrict__ ew_sum,
                             const int* __restrict__ batch, int* __restrict__ flag1) {
    __shared__ float wt[64 * 8];
    __shared__ float wsum[4];
    __shared__ unsigned short hs[NPB_F * 256];
    const int t = threadIdx.x;
    if (blockIdx.x < MLPB) {
        // ----- edge-MLP + histogram, 4 edges/thread -----
        if (t < 64) {
            #pragma unroll
            for (int i = 0; i < 5; ++i) wt[t * 8 + i] = w1[i * 64 + t];
            wt[t * 8 + 5] = b1[t];
            wt[t * 8 + 6] = w2[t];
            wt[t * 8 + 7] = 0.f;
        }
        __syncthreads();
        const int e0 = blockIdx.x * 1024 + t;
        float a0[4], a1[4], a2[4], a3[4], a4[4], acc[4];
        #pragma unroll
        for (int m = 0; m < 4; ++m) {
            int e = e0 + 256 * m;
            if (e < NE) {
                a0[m] = ea[e*5+0]; a1[m] = ea[e*5+1]; a2[m] = ea[e*5+2];
                a3[m] = ea[e*5+3]; a4[m] = ea[e*5+4];
            } else {
                a0[m] = a1[m] = a2[m] = a3[m] = a4[m] = 0.f;
            }
            acc[m] = b2[0];
        }
        int pos[4] = {0, 0, 0, 0};
        #pragma unroll
        for (int m = 0; m < 4; ++m) {
            int e = e0 + 256 * m;
            if (e < ET) {
                int d = (e < NE) ? ei_dst[e] : (e - NE);
                pos[m] = atomicAdd(&deg[d], 1);
            }
        }
        #pragma unroll 4
        for (int j = 0; j < 64; ++j) {
            const float4 lo = *(const float4*)&wt[j * 8];
            const float4 hi = *(const float4*)&wt[j * 8 + 4];
            #pragma unroll
            for (int m = 0; m < 4; ++m) {
                float hj = hi.y + a0[m]*lo.x + a1[m]*lo.y + a2[m]*lo.z + a3[m]*lo.w + a4[m]*hi.x;
                acc[m] += fmaxf(hj, 0.f) * hi.z;
            }
        }
        float vsum = 0.f;
        #pragma unroll
        for (int m = 0; m < 4; ++m) {
            int e = e0 + 256 * m;
            if (e < NE) {
                float val = 1.f / (1.f + __expf(-acc[m]));
                ewp[e] = make_int2(pos[m], __float_as_int(val));
                vsum += val;
            } else if (e < ET) {
                ewp[e] = make_int2(pos[m], 0);
            }
        }
        #pragma unroll
        for (int m = 1; m <= 32; m <<= 1) vsum += __shfl_xor(vsum, m);
        if ((t & 63) == 0) wsum[t >> 6] = vsum;
        __syncthreads();
        if (t == 0) atomicAdd(ew_sum, (wsum[0] + wsum[1]) + (wsum[2] + wsum[3]));
    } else if (blockIdx.x < MLPB + MRKB) {
        // ----- mark1 edge-scan: flags only (idempotent plain stores) -----
        int e = (blockIdx.x - MLPB) * 256 + t;
        if (e < ET) {
            int d, s;
            if (e < NE) { d = ei_dst[e]; s = ei_src[e]; } else { d = s = e - NE; }
            bool is_t = (d == 0) || (batch[d] != batch[d - 1]);
            if (is_t) flag1[s] = 1;
        }
    } else {
        // ----- node_transform, FIN=16, NPB_F=32 (clamped last block) -----
        const int FIN = 16;
        const int n0 = (blockIdx.x - MLPB - MRKB) * NPB_F;
        size_t xbase[NPB_F];
        #pragma unroll
        for (int i = 0; i < NPB_F; ++i)
            xbase[i] = (size_t)min(n0 + i, NN - 1) * FIN;   // clamp -> bit-identical dup
        float acc[NPB_F];
        #pragma unroll
        for (int i = 0; i < NPB_F; ++i) acc[i] = 0.f;
        #pragma unroll 4
        for (int k = 0; k < FIN; ++k) {
            float wv = W[k * 256 + t];
            #pragma unroll
            for (int i = 0; i < NPB_F; ++i)
                acc[i] += xin[xbase[i] + k] * wv;   // uniform address
        }
        int lane = t & 63, head = t >> 6;
        #pragma unroll
        for (int i = 0; i < NPB_F; ++i) hs[i * 256 + t] = f2bf(acc[i]);
        alpha_reduce_store<NPB_F>(acc, a_s[t], a_d[t], lane, head,
                                  [&](int i) { return min(n0 + i, NN - 1); }, asrc, adst);
        __syncthreads();
        #pragma unroll
        for (int j = 0; j < NPB_F / 8; ++j) {
            int idx = t + 256 * j;
            int row = n0 + (idx >> 5);          // 32 uint4 per 512B row
            if (row < NN)
                ((uint4*)(hb + (size_t)n0 * 256))[idx] = ((const uint4*)hs)[idx];
        }
    }
}

// ---------------- mark2: flags only, plain stores (needs flag1 complete) ----------------
__global__ void mark2_kernel(const int* __restrict__ ei_src, const int* __restrict__ ei_dst,
                             const int* __restrict__ flag1, int* __restrict__ flag2) {
    int e = blockIdx.x * 256 + threadIdx.x;
    if (e >= ET) return;
    int d, s;
    if (e < NE) { d = ei_dst[e]; s = ei_src[e]; } else { d = s = e - NE; }
    if (flag1[d]) flag2[s] = 1;           // idempotent plain store
}

// ---------------- scan phase A (+ ce prep + flag->list compaction, R20-proven) ----------------
__global__ void scan_blocks(const int* __restrict__ deg, int* __restrict__ row_ptr,
                            int* __restrict__ bsum,
                            const float* __restrict__ We, const float* __restrict__ att_e,
                            float* __restrict__ ce,
                            const int* __restrict__ flag1, const int* __restrict__ flag2,
                            int* __restrict__ list1, int* __restrict__ list2,
                            int* __restrict__ cnt1, int* __restrict__ cnt2) {
    __shared__ int sdata[SCAN_B];
    __shared__ int wt1[16], wt2[16];
    __shared__ int base1_s, base2_s;
    int t = threadIdx.x;
    int i = blockIdx.x * SCAN_B + t;
    if (i < 12) {
        int l = i >> 2, h = i & 3;
        float s = 0.f;
        for (int c = 0; c < 64; ++c)
            s += We[l*256 + h*64 + c] * att_e[l*256 + h*64 + c];
        ce[i] = s;
    }
    int v = (i < NN) ? deg[i] : 0;
    sdata[t] = v;
    __syncthreads();
    for (int off = 1; off < SCAN_B; off <<= 1) {
        int tv = (t >= off) ? sdata[t - off] : 0;
        __syncthreads();
        sdata[t] += tv;
        __syncthreads();
    }
    if (i < NN) row_ptr[i + 1] = sdata[t];
    if (t == SCAN_B - 1) bsum[blockIdx.x] = sdata[t];

    // ---- flag compaction (order within lists irrelevant; one atomic/block/list) ----
    int f1 = (i < NN) ? flag1[i] : 0;
    int f2 = (i < NN) ? flag2[i] : 0;
    int lane = t & 63, w = t >> 6;
    unsigned long long b1 = __ballot(f1 != 0);
    unsigned long long b2 = __ballot(f2 != 0);
    unsigned long long below = (lane == 0) ? 0ull : (~0ull >> (64 - lane));
    int r1 = __popcll(b1 & below);
    int r2 = __popcll(b2 & below);
    if (lane == 0) { wt1[w] = __popcll(b1); wt2[w] = __popcll(b2); }
    __syncthreads();
    if (t == 0) {
        int s1 = 0, s2 = 0;
        #pragma unroll
        for (int k = 0; k < 16; ++k) {
            int a = wt1[k]; wt1[k] = s1; s1 += a;
            int b = wt2[k]; wt2[k] = s2; s2 += b;
        }
        base1_s = s1 ? atomicAdd(cnt1, s1) : 0;
        base2_s = s2 ? atomicAdd(cnt2, s2) : 0;
    }
    __syncthreads();
    if (f1) list1[base1_s + wt1[w] + r1] = i;
    if (f2) list2[base2_s + wt2[w] + r2] = i;
}

__global__ void scan_fixup(const int* __restrict__ bsum, int* __restrict__ row_ptr) {
    __shared__ int sboff[64];
    int t = threadIdx.x;   // 256
    if (t < 64) {
        int v = (t < NBLK) ? bsum[t] : 0;
        int inc = v;
        #pragma unroll
        for (int off = 1; off < 64; off <<= 1) {
            int n = __shfl_up(inc, off);
            if (t >= off) inc += n;
        }
        sboff[t] = inc - v;   // exclusive scan
    }
    __syncthreads();
    int i = blockIdx.x * 256 + t;
    if (i < NN) row_ptr[i + 1] += sboff[i >> 10];
    if (i == 0) row_ptr[0] = 0;
}

// cone-only atomic-free scatter: only edges whose dst is in S2 are ever read back.
__global__ void scatter_kernel(const int* __restrict__ ei_src, const int* __restrict__ ei_dst,
                               const int* __restrict__ row_ptr, const int2* __restrict__ ewp,
                               const float* __restrict__ ew_sum, const int* __restrict__ flag2,
                               int2* __restrict__ csr) {
    int e = blockIdx.x * 256 + threadIdx.x;
    if (e >= ET) return;
    int d = (e < NE) ? ei_dst[e] : (e - NE);
    if (!flag2[d]) return;                 // flag2 is L2-resident (200 KB)
    int2 pw = ewp[e];
    int s, wbits;
    if (e < NE) {
        s = ei_src[e];
        wbits = pw.y;
    } else {
        s = d;
        wbits = __float_as_int(ew_sum[0] * (1.f / (float)NE));
    }
    csr[row_ptr[d] + pw.x] = make_int2(s, wbits);
}

// ---------------- list-restricted transform (h = xi @ W, FIN=64) ----------------
__global__ void transform64_list(const int* __restrict__ list, const int* __restrict__ cnt,
                                 const float* __restrict__ xin, const float* __restrict__ W,
                                 const float* __restrict__ a_s, const float* __restrict__ a_d,
                                 unsigned short* __restrict__ hb, float* __restrict__ asrc,
                                 float* __restrict__ adst) {
    const int t = threadIdx.x;
    const int n0 = blockIdx.x * NPB_T;
    const int nv = min(cnt[0], NN);
    if (n0 >= nv) return;
    __shared__ unsigned short hs[NPB_T * 256];
    __shared__ int nls[NPB_T];
    if (t < NPB_T) nls[t] = list[min(n0 + t, nv - 1)];  // clamp -> benign duplicates
    __syncthreads();
    int nreg[NPB_T];
    #pragma unroll
    for (int i = 0; i < NPB_T; ++i) nreg[i] = nls[i];
    float acc[NPB_T];
    #pragma unroll
    for (int i = 0; i < NPB_T; ++i) acc[i] = 0.f;
    #pragma unroll 4
    for (int k = 0; k < 64; ++k) {
        float wv = W[k * 256 + t];
        #pragma unroll
        for (int i = 0; i < NPB_T; ++i)
            acc[i] += xin[(size_t)nreg[i] * 64 + k] * wv;   // wave-uniform address
    }
    int lane = t & 63, head = t >> 6;
    #pragma unroll
    for (int i = 0; i < NPB_T; ++i) hs[i * 256 + t] = f2bf(acc[i]);
    alpha_reduce_store<NPB_T>(acc, a_s[t], a_d[t], lane, head,
                              [&](int i) { return nls[i]; }, asrc, adst);
    __syncthreads();
    int nn = nls[t >> 5];
    ((uint4*)(hb + (size_t)nn * 256))[t & 31] = ((const uint4*)hs)[t];
}

// ---------------- list-restricted aggregation ----------------
__global__ void gat_aggregate_list(const int* __restrict__ list, const int* __restrict__ cnt,
                                   const unsigned short* __restrict__ hb,
                                   const float* __restrict__ asrc, const float* __restrict__ adst,
                                   const int2* __restrict__ csr, const float* __restrict__ ce_l,
                                   const float* __restrict__ bias_l,
                                   const int* __restrict__ row_ptr,
                                   float* __restrict__ xi, int residual) {
    int idx = (blockIdx.x * 256 + threadIdx.x) >> 6;
    int n = min(cnt[0], NN);
    if (idx >= n) return;
    int widx = list[idx];
    int lane = threadIdx.x & 63;
    aggregate_one_node<false>(widx, lane, hb, asrc, adst, csr, ce_l, bias_l, row_ptr,
                              xi, residual, nullptr);
}

// ---------------- fused tail: aggregate(layer 2, 50 targets) + LN + 2-layer MLP ----------
__global__ void readout_fused(const int* __restrict__ batch,
                              const unsigned short* __restrict__ hb,
                              const float* __restrict__ asrc, const float* __restrict__ adst,
                              const int2* __restrict__ csr, const float* __restrict__ ce_l,
                              const float* __restrict__ bias_l, const int* __restrict__ row_ptr,
                              float* __restrict__ xi,
                              const float* __restrict__ ln_g, const float* __restrict__ ln_b,
                              const float* __restrict__ l1w, const float* __restrict__ l1b,
                              const float* __restrict__ l2w, const float* __restrict__ l2b,
                              float* __restrict__ out) {
    int b = blockIdx.x;
    int t = threadIdx.x;   // 64 threads, one wave
    __shared__ int tg_s;
    __shared__ float xs[64];
    if (t == 0) {
        int lo = 0, hi = NN;
        while (lo < hi) {
            int mid = (lo + hi) >> 1;
            if (batch[mid] < b) lo = mid + 1; else hi = mid;
        }
        tg_s = lo;
    }
    __syncthreads();
    int tg = tg_s;
    aggregate_one_node<true>(tg, t, hb, asrc, adst, csr, ce_l, bias_l, row_ptr, xi, 1, xs);
    __syncthreads();
    float x = xs[t];
    float s = x;
    #pragma unroll
    for (int mask = 1; mask <= 32; mask <<= 1) s += __shfl_xor(s, mask);
    float mu = s * (1.f / 64.f);
    float d = x - mu;
    float v = d * d;
    #pragma unroll
    for (int mask = 1; mask <= 32; mask <<= 1) v += __shfl_xor(v, mask);
    float var = v * (1.f / 64.f);
    float xn = d * rsqrtf(var + 1e-5f) * ln_g[t] + ln_b[t];
    __syncthreads();
    xs[t] = xn;
    __syncthreads();
    float acc = l1b[t];
    for (int k = 0; k < 64; ++k) acc += xs[k] * l1w[k * 64 + t];
    acc = eluf(acc);
    __shared__ float st[64];
    st[t] = acc;
    __syncthreads();
    if (t < 3) {
        float o = l2b[t];
        for (int k = 0; k < 64; ++k) o += st[k] * l2w[k * 3 + t];
        out[b * 3 + t] = o;
    }
}

extern "C" void kernel_launch(void* const* d_in, const int* in_sizes, int n_in,
                              void* d_out, int out_size, void* d_ws, size_t ws_size,
                              hipStream_t stream) {
    const float* x        = (const float*)d_in[0];
    const int*   ei       = (const int*)d_in[1];
    const float* ea       = (const float*)d_in[2];
    const int*   batch    = (const int*)d_in[3];
    const float* ee_w1    = (const float*)d_in[4];
    const float* ee_b1    = (const float*)d_in[5];
    const float* ee_w2    = (const float*)d_in[6];
    const float* ee_b2    = (const float*)d_in[7];
    const float* W1       = (const float*)d_in[8];
    const float* Ws       = (const float*)d_in[9];
    const float* att_src  = (const float*)d_in[10];
    const float* att_dst  = (const float*)d_in[11];
    const float* We       = (const float*)d_in[12];
    const float* att_e    = (const float*)d_in[13];
    const float* bias     = (const float*)d_in[14];
    const float* ln_g     = (const float*)d_in[15];
    const float* ln_b     = (const float*)d_in[16];
    const float* lin1_w   = (const float*)d_in[17];
    const float* lin1_b   = (const float*)d_in[18];
    const float* lin2_w   = (const float*)d_in[19];
    const float* lin2_b   = (const float*)d_in[20];
    float* out = (float*)d_out;

    // ---- workspace carve-up (256B aligned) ----
    char* ws = (char*)d_ws;
    size_t off = 0;
    auto alloc = [&](size_t bytes) -> char* {
        char* p = ws + off;
        off += (bytes + 255) & ~(size_t)255;
        return p;
    };
    int2*  ewp     = (int2*)alloc((size_t)ET * 8);
    float* ce      = (float*)alloc(12 * 4);
    unsigned short* hbuf = (unsigned short*)alloc((size_t)NN * 256 * 2);
    float* asrc    = (float*)alloc((size_t)NN * 4 * 4);
    float* adst    = (float*)alloc((size_t)NN * 4 * 4);
    float* xi      = (float*)alloc((size_t)NN * 64 * 4);
    // zeroed region: deg | flag1 | flag2 | misc(ew_sum, cnt1, cnt2)
    int*   deg     = (int*)alloc(((size_t)NN * 3 + 64) * 4);
    int*   flag1   = deg + NN;
    int*   flag2   = deg + 2 * NN;
    float* ew_sum  = (float*)(deg + 3 * NN);
    int*   cnt1    = deg + 3 * NN + 1;
    int*   cnt2    = deg + 3 * NN + 2;
    int*   row_ptr = (int*)alloc((size_t)(NN + 1) * 4);
    int*   bsum    = (int*)alloc(64 * 4);
    int2*  csr     = (int2*)alloc((size_t)ET * 8);
    int*   list1   = (int*)alloc((size_t)NN * 4);
    int*   list2   = (int*)alloc((size_t)NN * 4);
    (void)ws_size; (void)n_in; (void)in_sizes; (void)out_size;

    const int* ei_src = ei;
    const int* ei_dst = ei + NE;

    // 1. front: edge-MLP/hist + mark1 flags + node_transform<16> (one dispatch, MLP first)
    hipMemsetAsync(deg, 0, ((size_t)NN * 3 + 64) * 4, stream);
    front_kernel<<<MLPB + MRKB + NTB_F, 256, 0, stream>>>(
        x, W1, att_src + 0 * 256, att_dst + 0 * 256, hbuf, asrc, adst,
        ea, ee_w1, ee_b1, ee_w2, ee_b2, ei_src, ei_dst, deg, ewp, ew_sum,
        batch, flag1);

    // 2. mark2 flags (needs flag1), then scan (+ list compaction), fixup, cone scatter
    mark2_kernel<<<(ET + 255) / 256, 256, 0, stream>>>(ei_src, ei_dst, flag1, flag2);
    scan_blocks<<<NBLK, SCAN_B, 0, stream>>>(deg, row_ptr, bsum, We, att_e, ce,
                                             flag1, flag2, list1, list2, cnt1, cnt2);
    scan_fixup<<<(NN + 255) / 256, 256, 0, stream>>>(bsum, row_ptr);
    scatter_kernel<<<(ET + 255) / 256, 256, 0, stream>>>(ei_src, ei_dst, row_ptr, ewp,
                                                         ew_sum, flag2, csr);

    // 3. GAT layers restricted to the cone (identical arithmetic per node)
    gat_aggregate_list<<<(NN + 3) / 4, 256, 0, stream>>>(list2, cnt2, hbuf, asrc, adst,
                                                         csr, ce + 0 * 4, bias + 0 * 64,
                                                         row_ptr, xi, 0);
    transform64_list<<<NN / NPB_T, 256, 0, stream>>>(list2, cnt2, xi, Ws + 0 * 64 * 256,
                                                     att_src + 1 * 256, att_dst + 1 * 256,
                                                     hbuf, asrc, adst);
    gat_aggregate_list<<<(NN + 3) / 4, 256, 0, stream>>>(list1, cnt1, hbuf, asrc, adst,
                                                         csr, ce + 1 * 4, bias + 1 * 64,
                                                         row_ptr, xi, 1);
    transform64_list<<<NN / NPB_T, 256, 0, stream>>>(list1, cnt1, xi, Ws + 1 * 64 * 256,
                                                     att_src + 2 * 256, att_dst + 2 * 256,
                                                     hbuf, asrc, adst);

    // 4. fused tail: aggregate layer-2 over the 50 targets + LN + MLP
    readout_fused<<<NB, 64, 0, stream>>>(batch, hbuf, asrc, adst, csr, ce + 2 * 4,
                                         bias + 2 * 64, row_ptr, xi,
                                         ln_g, ln_b, lin1_w, lin1_b, lin2_w, lin2_b, out);
}

// Round 11
// 261.677 us; speedup vs baseline: 1.0455x; 1.0455x over previous
//
#include <hip/hip_runtime.h>
#include <cstddef>
#include <cstdint>

constexpr int NN = 50000;          // nodes
constexpr int NE = 800000;         // edges (no self loops)
constexpr int ET = NE + NN;        // edges + self loops
constexpr int NB = 50;             // graphs
constexpr int SCAN_B = 1024;
constexpr int NBLK = (NN + SCAN_B - 1) / SCAN_B;   // 49
constexpr int NPB_F = 16;                          // nodes/block, front node branch (R12/R20-proven; 32 regressed R21)
constexpr int NPB_T = 8;                           // nodes/block, transform (R12-proven)
constexpr int NTB_F = NN / NPB_F;                  // front node blocks (3125)
constexpr int MLPB = (ET + 1023) / 1024;           // edge-mlp blocks (4 edges/thread)
constexpr int MRKB  = (ET + 255) / 256;            // mark1 edge-scan blocks (256 thr)

typedef float v2f __attribute__((ext_vector_type(2)));

__device__ __forceinline__ float eluf(float x) { return x > 0.f ? x : expm1f(x); }

// round-to-nearest-even fp32 -> bf16 (as ushort)
__device__ __forceinline__ unsigned short f2bf(float f) {
    unsigned int u = __float_as_uint(f);
    unsigned int r = (u + 0x7fffu + ((u >> 16) & 1u)) >> 16;
    return (unsigned short)r;
}

// Interleaved 4-node {vs,vd} reduction over 64 lanes (R14-proven).
template <int NPB, typename NodeOf>
__device__ __forceinline__ void alpha_reduce_store(const float* acc, float as_t, float ad_t,
                                                   int lane, int head, NodeOf nodeOf,
                                                   float* __restrict__ asrc,
                                                   float* __restrict__ adst) {
    #pragma unroll
    for (int g = 0; g < NPB; g += 4) {
        float x0, x1, x2, x3;
        {
            float vs, vd;
            vs = acc[g + 0] * as_t; vd = acc[g + 0] * ad_t;
            x0 = ((lane & 1) ? vd : vs) + __shfl_xor((lane & 1) ? vs : vd, 1);
            vs = acc[g + 1] * as_t; vd = acc[g + 1] * ad_t;
            x1 = ((lane & 1) ? vd : vs) + __shfl_xor((lane & 1) ? vs : vd, 1);
            vs = acc[g + 2] * as_t; vd = acc[g + 2] * ad_t;
            x2 = ((lane & 1) ? vd : vs) + __shfl_xor((lane & 1) ? vs : vd, 1);
            vs = acc[g + 3] * as_t; vd = acc[g + 3] * ad_t;
            x3 = ((lane & 1) ? vd : vs) + __shfl_xor((lane & 1) ? vs : vd, 1);
        }
        float y0 = ((lane & 2) ? x1 : x0) + __shfl_xor((lane & 2) ? x0 : x1, 2);
        float y1 = ((lane & 2) ? x3 : x2) + __shfl_xor((lane & 2) ? x2 : x3, 2);
        float z  = ((lane & 4) ? y1 : y0) + __shfl_xor((lane & 4) ? y0 : y1, 4);
        z += __shfl_xor(z, 8);
        z += __shfl_xor(z, 16);
        z += __shfl_xor(z, 32);
        if (lane < 8) {
            int node = nodeOf(g + (lane >> 1));
            if (lane & 1) adst[node * 4 + head] = z;
            else          asrc[node * 4 + head] = z;
        }
    }
}

// ---------------- per-node aggregation body (R9 2-deep two-half structure) ----------------
// WRITE_LDS: also deposit the elu'd output row into xs_row (for the fused readout).
template <bool WRITE_LDS>
__device__ __forceinline__ void aggregate_one_node(
        int widx, int lane,
        const unsigned short* __restrict__ hb,
        const float* __restrict__ asrc, const float* __restrict__ adst,
        const int2* __restrict__ csr, const float* __restrict__ ce_l,
        const float* __restrict__ bias_l, const int* __restrict__ row_ptr,
        float* __restrict__ xi, int residual, float* xs_row) {
    int half = lane >> 5;
    int li = lane & 31;        // channels li*8 .. li*8+7
    int head = li >> 3;        // head
    int start = row_ptr[widx], end = row_ptr[widx + 1];
    float adw = adst[widx * 4 + head];
    float ceh = ce_l[head];
    const uint4* hbv = (const uint4*)hb;

    v2f acc2[4];
    #pragma unroll
    for (int r = 0; r < 4; ++r) { acc2[r].x = 0.f; acc2[r].y = 0.f; }
    float psum = 0.f;

    #define PROC(EI)                                                                  \
        {                                                                             \
            const int2 se = csr[EI];                                                  \
            int s = se.x;                                                             \
            float w = __int_as_float(se.y);                                           \
            const uint4 q = hbv[(unsigned)s * 32u + (unsigned)li];                    \
            float v = asrc[s * 4 + head] + adw + w * ceh;                             \
            v = v > 0.f ? v : 0.2f * v;                                               \
            float p = __expf(v);                                                      \
            psum += p;                                                                \
            v2f pv; pv.x = p; pv.y = p;                                               \
            v2f h0; h0.x = __uint_as_float(q.x << 16); h0.y = __uint_as_float(q.x & 0xffff0000u); \
            v2f h1; h1.x = __uint_as_float(q.y << 16); h1.y = __uint_as_float(q.y & 0xffff0000u); \
            v2f h2; h2.x = __uint_as_float(q.z << 16); h2.y = __uint_as_float(q.z & 0xffff0000u); \
            v2f h3; h3.x = __uint_as_float(q.w << 16); h3.y = __uint_as_float(q.w & 0xffff0000u); \
            acc2[0] += pv * h0;                                                       \
            acc2[1] += pv * h1;                                                       \
            acc2[2] += pv * h2;                                                       \
            acc2[3] += pv * h3;                                                       \
        }

    int ei = start + half;
    for (; ei + 2 < end; ei += 4) {   // 2 edges per half per iter -> 2 gathers in flight
        PROC(ei);
        PROC(ei + 2);
    }
    if (ei < end) PROC(ei);
    #undef PROC

    float acc[8];
    acc[0] = acc2[0].x; acc[1] = acc2[0].y; acc[2] = acc2[1].x; acc[3] = acc2[1].y;
    acc[4] = acc2[2].x; acc[5] = acc2[2].y; acc[6] = acc2[3].x; acc[7] = acc2[3].y;

    psum += __shfl_xor(psum, 32);
    #pragma unroll
    for (int r = 0; r < 8; ++r) acc[r] += __shfl_xor(acc[r], 32);

    float inv = 1.f / (psum + 1e-16f);
    #pragma unroll
    for (int r = 0; r < 8; ++r) acc[r] *= inv;

    #pragma unroll
    for (int r = 0; r < 8; ++r) {
        acc[r] += __shfl_xor(acc[r], 8);
        acc[r] += __shfl_xor(acc[r], 16);
        acc[r] *= 0.25f;
    }

    if (lane < 8) {
        int c0 = lane * 8;
        const float4 b0 = *(const float4*)(bias_l + c0);
        const float4 b1 = *(const float4*)(bias_l + c0 + 4);
        float4 v0, v1;
        v0.x = acc[0] + b0.x; v0.y = acc[1] + b0.y; v0.z = acc[2] + b0.z; v0.w = acc[3] + b0.w;
        v1.x = acc[4] + b1.x; v1.y = acc[5] + b1.y; v1.z = acc[6] + b1.z; v1.w = acc[7] + b1.w;
        float* xo = xi + (size_t)widx * 64 + c0;
        if (residual) {
            const float4 p0 = *(const float4*)xo;
            const float4 p1 = *(const float4*)(xo + 4);
            v0.x += p0.x; v0.y += p0.y; v0.z += p0.z; v0.w += p0.w;
            v1.x += p1.x; v1.y += p1.y; v1.z += p1.z; v1.w += p1.w;
        }
        v0.x = eluf(v0.x); v0.y = eluf(v0.y); v0.z = eluf(v0.z); v0.w = eluf(v0.w);
        v1.x = eluf(v1.x); v1.y = eluf(v1.y); v1.z = eluf(v1.z); v1.w = eluf(v1.w);
        *(float4*)xo = v0;
        *(float4*)(xo + 4) = v1;
        if (WRITE_LDS) {
            *(float4*)(xs_row + c0) = v0;
            *(float4*)(xs_row + c0 + 4) = v1;
        }
    }
}

// ---------------- front dispatch (R22): edge-MLP+hist | mark1 flags | node_transform<16> ----
// MLP (long serial chains) first; numerous short node blocks pack the dispatch tail.
// Node branch is the R20-proven NPB_F=16 body (NPB_F=32 regressed: LDS 19KB -> occupancy).
__global__ void front_kernel(const float* __restrict__ xin, const float* __restrict__ W,
                             const float* __restrict__ a_s, const float* __restrict__ a_d,
                             unsigned short* __restrict__ hb, float* __restrict__ asrc,
                             float* __restrict__ adst,
                             const float* __restrict__ ea,
                             const float* __restrict__ w1, const float* __restrict__ b1,
                             const float* __restrict__ w2, const float* __restrict__ b2,
                             const int* __restrict__ ei_src, const int* __restrict__ ei_dst,
                             int* __restrict__ deg,
                             int2* __restrict__ ewp, float* __restrict__ ew_sum,
                             const int* __restrict__ batch, int* __restrict__ flag1) {
    __shared__ float wt[64 * 8];
    __shared__ float wsum[4];
    __shared__ unsigned short hs[NPB_F * 256];
    const int t = threadIdx.x;
    if (blockIdx.x < MLPB) {
        // ----- edge-MLP + histogram, 4 edges/thread -----
        if (t < 64) {
            #pragma unroll
            for (int i = 0; i < 5; ++i) wt[t * 8 + i] = w1[i * 64 + t];
            wt[t * 8 + 5] = b1[t];
            wt[t * 8 + 6] = w2[t];
            wt[t * 8 + 7] = 0.f;
        }
        __syncthreads();
        const int e0 = blockIdx.x * 1024 + t;
        float a0[4], a1[4], a2[4], a3[4], a4[4], acc[4];
        #pragma unroll
        for (int m = 0; m < 4; ++m) {
            int e = e0 + 256 * m;
            if (e < NE) {
                a0[m] = ea[e*5+0]; a1[m] = ea[e*5+1]; a2[m] = ea[e*5+2];
                a3[m] = ea[e*5+3]; a4[m] = ea[e*5+4];
            } else {
                a0[m] = a1[m] = a2[m] = a3[m] = a4[m] = 0.f;
            }
            acc[m] = b2[0];
        }
        int pos[4] = {0, 0, 0, 0};
        #pragma unroll
        for (int m = 0; m < 4; ++m) {
            int e = e0 + 256 * m;
            if (e < ET) {
                int d = (e < NE) ? ei_dst[e] : (e - NE);
                pos[m] = atomicAdd(&deg[d], 1);
            }
        }
        #pragma unroll 4
        for (int j = 0; j < 64; ++j) {
            const float4 lo = *(const float4*)&wt[j * 8];
            const float4 hi = *(const float4*)&wt[j * 8 + 4];
            #pragma unroll
            for (int m = 0; m < 4; ++m) {
                float hj = hi.y + a0[m]*lo.x + a1[m]*lo.y + a2[m]*lo.z + a3[m]*lo.w + a4[m]*hi.x;
                acc[m] += fmaxf(hj, 0.f) * hi.z;
            }
        }
        float vsum = 0.f;
        #pragma unroll
        for (int m = 0; m < 4; ++m) {
            int e = e0 + 256 * m;
            if (e < NE) {
                float val = 1.f / (1.f + __expf(-acc[m]));
                ewp[e] = make_int2(pos[m], __float_as_int(val));
                vsum += val;
            } else if (e < ET) {
                ewp[e] = make_int2(pos[m], 0);
            }
        }
        #pragma unroll
        for (int m = 1; m <= 32; m <<= 1) vsum += __shfl_xor(vsum, m);
        if ((t & 63) == 0) wsum[t >> 6] = vsum;
        __syncthreads();
        if (t == 0) atomicAdd(ew_sum, (wsum[0] + wsum[1]) + (wsum[2] + wsum[3]));
    } else if (blockIdx.x < MLPB + MRKB) {
        // ----- mark1 edge-scan: flags only (idempotent plain stores) -----
        int e = (blockIdx.x - MLPB) * 256 + t;
        if (e < ET) {
            int d, s;
            if (e < NE) { d = ei_dst[e]; s = ei_src[e]; } else { d = s = e - NE; }
            bool is_t = (d == 0) || (batch[d] != batch[d - 1]);
            if (is_t) flag1[s] = 1;
        }
    } else {
        // ----- node_transform, FIN=16, NPB_F=16 (R20-proven body) -----
        const int FIN = 16;
        const int n0 = (blockIdx.x - MLPB - MRKB) * NPB_F;
        float acc[NPB_F];
        #pragma unroll
        for (int i = 0; i < NPB_F; ++i) acc[i] = 0.f;
        #pragma unroll 4
        for (int k = 0; k < FIN; ++k) {
            float wv = W[k * 256 + t];
            #pragma unroll
            for (int i = 0; i < NPB_F; ++i)
                acc[i] += xin[(size_t)(n0 + i) * FIN + k] * wv;   // uniform address
        }
        int lane = t & 63, head = t >> 6;
        #pragma unroll
        for (int i = 0; i < NPB_F; ++i) hs[i * 256 + t] = f2bf(acc[i]);
        alpha_reduce_store<NPB_F>(acc, a_s[t], a_d[t], lane, head,
                                  [&](int i) { return n0 + i; }, asrc, adst);
        __syncthreads();
        ((uint4*)(hb + (size_t)n0 * 256))[t]       = ((const uint4*)hs)[t];
        ((uint4*)(hb + (size_t)n0 * 256))[t + 256] = ((const uint4*)hs)[t + 256];
    }
}

// ---------------- mark2: flags only, plain stores (needs flag1 complete) ----------------
__global__ void mark2_kernel(const int* __restrict__ ei_src, const int* __restrict__ ei_dst,
                             const int* __restrict__ flag1, int* __restrict__ flag2) {
    int e = blockIdx.x * 256 + threadIdx.x;
    if (e >= ET) return;
    int d, s;
    if (e < NE) { d = ei_dst[e]; s = ei_src[e]; } else { d = s = e - NE; }
    if (flag1[d]) flag2[s] = 1;           // idempotent plain store
}

// ---------------- scan phase A (+ ce prep + flag->list compaction, R20-proven) ----------------
__global__ void scan_blocks(const int* __restrict__ deg, int* __restrict__ row_ptr,
                            int* __restrict__ bsum,
                            const float* __restrict__ We, const float* __restrict__ att_e,
                            float* __restrict__ ce,
                            const int* __restrict__ flag1, const int* __restrict__ flag2,
                            int* __restrict__ list1, int* __restrict__ list2,
                            int* __restrict__ cnt1, int* __restrict__ cnt2) {
    __shared__ int sdata[SCAN_B];
    __shared__ int wt1[16], wt2[16];
    __shared__ int base1_s, base2_s;
    int t = threadIdx.x;
    int i = blockIdx.x * SCAN_B + t;
    if (i < 12) {
        int l = i >> 2, h = i & 3;
        float s = 0.f;
        for (int c = 0; c < 64; ++c)
            s += We[l*256 + h*64 + c] * att_e[l*256 + h*64 + c];
        ce[i] = s;
    }
    int v = (i < NN) ? deg[i] : 0;
    sdata[t] = v;
    __syncthreads();
    for (int off = 1; off < SCAN_B; off <<= 1) {
        int tv = (t >= off) ? sdata[t - off] : 0;
        __syncthreads();
        sdata[t] += tv;
        __syncthreads();
    }
    if (i < NN) row_ptr[i + 1] = sdata[t];
    if (t == SCAN_B - 1) bsum[blockIdx.x] = sdata[t];

    // ---- flag compaction (order within lists irrelevant; one atomic/block/list) ----
    int f1 = (i < NN) ? flag1[i] : 0;
    int f2 = (i < NN) ? flag2[i] : 0;
    int lane = t & 63, w = t >> 6;
    unsigned long long b1 = __ballot(f1 != 0);
    unsigned long long b2 = __ballot(f2 != 0);
    unsigned long long below = (lane == 0) ? 0ull : (~0ull >> (64 - lane));
    int r1 = __popcll(b1 & below);
    int r2 = __popcll(b2 & below);
    if (lane == 0) { wt1[w] = __popcll(b1); wt2[w] = __popcll(b2); }
    __syncthreads();
    if (t == 0) {
        int s1 = 0, s2 = 0;
        #pragma unroll
        for (int k = 0; k < 16; ++k) {
            int a = wt1[k]; wt1[k] = s1; s1 += a;
            int b = wt2[k]; wt2[k] = s2; s2 += b;
        }
        base1_s = s1 ? atomicAdd(cnt1, s1) : 0;
        base2_s = s2 ? atomicAdd(cnt2, s2) : 0;
    }
    __syncthreads();
    if (f1) list1[base1_s + wt1[w] + r1] = i;
    if (f2) list2[base2_s + wt2[w] + r2] = i;
}

__global__ void scan_fixup(const int* __restrict__ bsum, int* __restrict__ row_ptr) {
    __shared__ int sboff[64];
    int t = threadIdx.x;   // 256
    if (t < 64) {
        int v = (t < NBLK) ? bsum[t] : 0;
        int inc = v;
        #pragma unroll
        for (int off = 1; off < 64; off <<= 1) {
            int n = __shfl_up(inc, off);
            if (t >= off) inc += n;
        }
        sboff[t] = inc - v;   // exclusive scan
    }
    __syncthreads();
    int i = blockIdx.x * 256 + t;
    if (i < NN) row_ptr[i + 1] += sboff[i >> 10];
    if (i == 0) row_ptr[0] = 0;
}

// cone-only atomic-free scatter: only edges whose dst is in S2 are ever read back.
__global__ void scatter_kernel(const int* __restrict__ ei_src, const int* __restrict__ ei_dst,
                               const int* __restrict__ row_ptr, const int2* __restrict__ ewp,
                               const float* __restrict__ ew_sum, const int* __restrict__ flag2,
                               int2* __restrict__ csr) {
    int e = blockIdx.x * 256 + threadIdx.x;
    if (e >= ET) return;
    int d = (e < NE) ? ei_dst[e] : (e - NE);
    if (!flag2[d]) return;                 // flag2 is L2-resident (200 KB)
    int2 pw = ewp[e];
    int s, wbits;
    if (e < NE) {
        s = ei_src[e];
        wbits = pw.y;
    } else {
        s = d;
        wbits = __float_as_int(ew_sum[0] * (1.f / (float)NE));
    }
    csr[row_ptr[d] + pw.x] = make_int2(s, wbits);
}

// ---------------- list-restricted transform (h = xi @ W, FIN=64) ----------------
__global__ void transform64_list(const int* __restrict__ list, const int* __restrict__ cnt,
                                 const float* __restrict__ xin, const float* __restrict__ W,
                                 const float* __restrict__ a_s, const float* __restrict__ a_d,
                                 unsigned short* __restrict__ hb, float* __restrict__ asrc,
                                 float* __restrict__ adst) {
    const int t = threadIdx.x;
    const int n0 = blockIdx.x * NPB_T;
    const int nv = min(cnt[0], NN);
    if (n0 >= nv) return;
    __shared__ unsigned short hs[NPB_T * 256];
    __shared__ int nls[NPB_T];
    if (t < NPB_T) nls[t] = list[min(n0 + t, nv - 1)];  // clamp -> benign duplicates
    __syncthreads();
    int nreg[NPB_T];
    #pragma unroll
    for (int i = 0; i < NPB_T; ++i) nreg[i] = nls[i];
    float acc[NPB_T];
    #pragma unroll
    for (int i = 0; i < NPB_T; ++i) acc[i] = 0.f;
    #pragma unroll 4
    for (int k = 0; k < 64; ++k) {
        float wv = W[k * 256 + t];
        #pragma unroll
        for (int i = 0; i < NPB_T; ++i)
            acc[i] += xin[(size_t)nreg[i] * 64 + k] * wv;   // wave-uniform address
    }
    int lane = t & 63, head = t >> 6;
    #pragma unroll
    for (int i = 0; i < NPB_T; ++i) hs[i * 256 + t] = f2bf(acc[i]);
    alpha_reduce_store<NPB_T>(acc, a_s[t], a_d[t], lane, head,
                              [&](int i) { return nls[i]; }, asrc, adst);
    __syncthreads();
    int nn = nls[t >> 5];
    ((uint4*)(hb + (size_t)nn * 256))[t & 31] = ((const uint4*)hs)[t];
}

// ---------------- list-restricted aggregation ----------------
__global__ void gat_aggregate_list(const int* __restrict__ list, const int* __restrict__ cnt,
                                   const unsigned short* __restrict__ hb,
                                   const float* __restrict__ asrc, const float* __restrict__ adst,
                                   const int2* __restrict__ csr, const float* __restrict__ ce_l,
                                   const float* __restrict__ bias_l,
                                   const int* __restrict__ row_ptr,
                                   float* __restrict__ xi, int residual) {
    int idx = (blockIdx.x * 256 + threadIdx.x) >> 6;
    int n = min(cnt[0], NN);
    if (idx >= n) return;
    int widx = list[idx];
    int lane = threadIdx.x & 63;
    aggregate_one_node<false>(widx, lane, hb, asrc, adst, csr, ce_l, bias_l, row_ptr,
                              xi, residual, nullptr);
}

// ---------------- fused tail: aggregate(layer 2, 50 targets) + LN + 2-layer MLP ----------
__global__ void readout_fused(const int* __restrict__ batch,
                              const unsigned short* __restrict__ hb,
                              const float* __restrict__ asrc, const float* __restrict__ adst,
                              const int2* __restrict__ csr, const float* __restrict__ ce_l,
                              const float* __restrict__ bias_l, const int* __restrict__ row_ptr,
                              float* __restrict__ xi,
                              const float* __restrict__ ln_g, const float* __restrict__ ln_b,
                              const float* __restrict__ l1w, const float* __restrict__ l1b,
                              const float* __restrict__ l2w, const float* __restrict__ l2b,
                              float* __restrict__ out) {
    int b = blockIdx.x;
    int t = threadIdx.x;   // 64 threads, one wave
    __shared__ int tg_s;
    __shared__ float xs[64];
    if (t == 0) {
        int lo = 0, hi = NN;
        while (lo < hi) {
            int mid = (lo + hi) >> 1;
            if (batch[mid] < b) lo = mid + 1; else hi = mid;
        }
        tg_s = lo;
    }
    __syncthreads();
    int tg = tg_s;
    aggregate_one_node<true>(tg, t, hb, asrc, adst, csr, ce_l, bias_l, row_ptr, xi, 1, xs);
    __syncthreads();
    float x = xs[t];
    float s = x;
    #pragma unroll
    for (int mask = 1; mask <= 32; mask <<= 1) s += __shfl_xor(s, mask);
    float mu = s * (1.f / 64.f);
    float d = x - mu;
    float v = d * d;
    #pragma unroll
    for (int mask = 1; mask <= 32; mask <<= 1) v += __shfl_xor(v, mask);
    float var = v * (1.f / 64.f);
    float xn = d * rsqrtf(var + 1e-5f) * ln_g[t] + ln_b[t];
    __syncthreads();
    xs[t] = xn;
    __syncthreads();
    float acc = l1b[t];
    for (int k = 0; k < 64; ++k) acc += xs[k] * l1w[k * 64 + t];
    acc = eluf(acc);
    __shared__ float st[64];
    st[t] = acc;
    __syncthreads();
    if (t < 3) {
        float o = l2b[t];
        for (int k = 0; k < 64; ++k) o += st[k] * l2w[k * 3 + t];
        out[b * 3 + t] = o;
    }
}

extern "C" void kernel_launch(void* const* d_in, const int* in_sizes, int n_in,
                              void* d_out, int out_size, void* d_ws, size_t ws_size,
                              hipStream_t stream) {
    const float* x        = (const float*)d_in[0];
    const int*   ei       = (const int*)d_in[1];
    const float* ea       = (const float*)d_in[2];
    const int*   batch    = (const int*)d_in[3];
    const float* ee_w1    = (const float*)d_in[4];
    const float* ee_b1    = (const float*)d_in[5];
    const float* ee_w2    = (const float*)d_in[6];
    const float* ee_b2    = (const float*)d_in[7];
    const float* W1       = (const float*)d_in[8];
    const float* Ws       = (const float*)d_in[9];
    const float* att_src  = (const float*)d_in[10];
    const float* att_dst  = (const float*)d_in[11];
    const float* We       = (const float*)d_in[12];
    const float* att_e    = (const float*)d_in[13];
    const float* bias     = (const float*)d_in[14];
    const float* ln_g     = (const float*)d_in[15];
    const float* ln_b     = (const float*)d_in[16];
    const float* lin1_w   = (const float*)d_in[17];
    const float* lin1_b   = (const float*)d_in[18];
    const float* lin2_w   = (const float*)d_in[19];
    const float* lin2_b   = (const float*)d_in[20];
    float* out = (float*)d_out;

    // ---- workspace carve-up (256B aligned) ----
    char* ws = (char*)d_ws;
    size_t off = 0;
    auto alloc = [&](size_t bytes) -> char* {
        char* p = ws + off;
        off += (bytes + 255) & ~(size_t)255;
        return p;
    };
    int2*  ewp     = (int2*)alloc((size_t)ET * 8);
    float* ce      = (float*)alloc(12 * 4);
    unsigned short* hbuf = (unsigned short*)alloc((size_t)NN * 256 * 2);
    float* asrc    = (float*)alloc((size_t)NN * 4 * 4);
    float* adst    = (float*)alloc((size_t)NN * 4 * 4);
    float* xi      = (float*)alloc((size_t)NN * 64 * 4);
    // zeroed region: deg | flag1 | flag2 | misc(ew_sum, cnt1, cnt2)
    int*   deg     = (int*)alloc(((size_t)NN * 3 + 64) * 4);
    int*   flag1   = deg + NN;
    int*   flag2   = deg + 2 * NN;
    float* ew_sum  = (float*)(deg + 3 * NN);
    int*   cnt1    = deg + 3 * NN + 1;
    int*   cnt2    = deg + 3 * NN + 2;
    int*   row_ptr = (int*)alloc((size_t)(NN + 1) * 4);
    int*   bsum    = (int*)alloc(64 * 4);
    int2*  csr     = (int2*)alloc((size_t)ET * 8);
    int*   list1   = (int*)alloc((size_t)NN * 4);
    int*   list2   = (int*)alloc((size_t)NN * 4);
    (void)ws_size; (void)n_in; (void)in_sizes; (void)out_size;

    const int* ei_src = ei;
    const int* ei_dst = ei + NE;

    // 1. front: edge-MLP/hist + mark1 flags + node_transform<16> (one dispatch, MLP first)
    hipMemsetAsync(deg, 0, ((size_t)NN * 3 + 64) * 4, stream);
    front_kernel<<<MLPB + MRKB + NTB_F, 256, 0, stream>>>(
        x, W1, att_src + 0 * 256, att_dst + 0 * 256, hbuf, asrc, adst,
        ea, ee_w1, ee_b1, ee_w2, ee_b2, ei_src, ei_dst, deg, ewp, ew_sum,
        batch, flag1);

    // 2. mark2 flags (needs flag1), then scan (+ list compaction), fixup, cone scatter
    mark2_kernel<<<(ET + 255) / 256, 256, 0, stream>>>(ei_src, ei_dst, flag1, flag2);
    scan_blocks<<<NBLK, SCAN_B, 0, stream>>>(deg, row_ptr, bsum, We, att_e, ce,
                                             flag1, flag2, list1, list2, cnt1, cnt2);
    scan_fixup<<<(NN + 255) / 256, 256, 0, stream>>>(bsum, row_ptr);
    scatter_kernel<<<(ET + 255) / 256, 256, 0, stream>>>(ei_src, ei_dst, row_ptr, ewp,
                                                         ew_sum, flag2, csr);

    // 3. GAT layers restricted to the cone (identical arithmetic per node)
    gat_aggregate_list<<<(NN + 3) / 4, 256, 0, stream>>>(list2, cnt2, hbuf, asrc, adst,
                                                         csr, ce + 0 * 4, bias + 0 * 64,
                                                         row_ptr, xi, 0);
    transform64_list<<<NN / NPB_T, 256, 0, stream>>>(list2, cnt2, xi, Ws + 0 * 64 * 256,
                                                     att_src + 1 * 256, att_dst + 1 * 256,
                                                     hbuf, asrc, adst);
    gat_aggregate_list<<<(NN + 3) / 4, 256, 0, stream>>>(list1, cnt1, hbuf, asrc, adst,
                                                         csr, ce + 1 * 4, bias + 1 * 64,
                                                         row_ptr, xi, 1);
    transform64_list<<<NN / NPB_T, 256, 0, stream>>>(list1, cnt1, xi, Ws + 1 * 64 * 256,
                                                     att_src + 2 * 256, att_dst + 2 * 256,
                                                     hbuf, asrc, adst);

    // 4. fused tail: aggregate layer-2 over the 50 targets + LN + MLP
    readout_fused<<<NB, 64, 0, stream>>>(batch, hbuf, asrc, adst, csr, ce + 2 * 4,
                                         bias + 2 * 64, row_ptr, xi,
                                         ln_g, ln_b, lin1_w, lin1_b, lin2_w, lin2_b, out);
}

// Round 12
// 255.879 us; speedup vs baseline: 1.0692x; 1.0227x over previous
//
#include <hip/hip_runtime.h>
#include <cstddef>
#include <cstdint>

constexpr int NN = 50000;          // nodes
constexpr int NE = 800000;         // edges (no self loops)
constexpr int ET = NE + NN;        // edges + self loops
constexpr int NB = 50;             // graphs
constexpr int SCAN_B = 1024;
constexpr int NBLK = (NN + SCAN_B - 1) / SCAN_B;   // 49
constexpr int NPB_F = 16;                          // nodes/block, front node branch (R12/R20-proven)
constexpr int NPB_T = 8;                           // nodes/block, transform (R12-proven)
constexpr int NTB_F = NN / NPB_F;                  // front node blocks (3125)
constexpr int MLPB = (ET + 1023) / 1024;           // edge-mlp blocks (4 edges/thread)

typedef float v2f __attribute__((ext_vector_type(2)));

__device__ __forceinline__ float eluf(float x) { return x > 0.f ? x : expm1f(x); }

// round-to-nearest-even fp32 -> bf16 (as ushort)
__device__ __forceinline__ unsigned short f2bf(float f) {
    unsigned int u = __float_as_uint(f);
    unsigned int r = (u + 0x7fffu + ((u >> 16) & 1u)) >> 16;
    return (unsigned short)r;
}

// Interleaved 4-node {vs,vd} reduction over 64 lanes (R14-proven).
template <int NPB, typename NodeOf>
__device__ __forceinline__ void alpha_reduce_store(const float* acc, float as_t, float ad_t,
                                                   int lane, int head, NodeOf nodeOf,
                                                   float* __restrict__ asrc,
                                                   float* __restrict__ adst) {
    #pragma unroll
    for (int g = 0; g < NPB; g += 4) {
        float x0, x1, x2, x3;
        {
            float vs, vd;
            vs = acc[g + 0] * as_t; vd = acc[g + 0] * ad_t;
            x0 = ((lane & 1) ? vd : vs) + __shfl_xor((lane & 1) ? vs : vd, 1);
            vs = acc[g + 1] * as_t; vd = acc[g + 1] * ad_t;
            x1 = ((lane & 1) ? vd : vs) + __shfl_xor((lane & 1) ? vs : vd, 1);
            vs = acc[g + 2] * as_t; vd = acc[g + 2] * ad_t;
            x2 = ((lane & 1) ? vd : vs) + __shfl_xor((lane & 1) ? vs : vd, 1);
            vs = acc[g + 3] * as_t; vd = acc[g + 3] * ad_t;
            x3 = ((lane & 1) ? vd : vs) + __shfl_xor((lane & 1) ? vs : vd, 1);
        }
        float y0 = ((lane & 2) ? x1 : x0) + __shfl_xor((lane & 2) ? x0 : x1, 2);
        float y1 = ((lane & 2) ? x3 : x2) + __shfl_xor((lane & 2) ? x2 : x3, 2);
        float z  = ((lane & 4) ? y1 : y0) + __shfl_xor((lane & 4) ? y0 : y1, 4);
        z += __shfl_xor(z, 8);
        z += __shfl_xor(z, 16);
        z += __shfl_xor(z, 32);
        if (lane < 8) {
            int node = nodeOf(g + (lane >> 1));
            if (lane & 1) adst[node * 4 + head] = z;
            else          asrc[node * 4 + head] = z;
        }
    }
}

// ---------------- per-node aggregation body (R9 2-deep two-half structure) ----------------
// WRITE_LDS: also deposit the elu'd output row into xs_row (for the fused readout).
template <bool WRITE_LDS>
__device__ __forceinline__ void aggregate_one_node(
        int widx, int lane,
        const unsigned short* __restrict__ hb,
        const float* __restrict__ asrc, const float* __restrict__ adst,
        const int2* __restrict__ csr, const float* __restrict__ ce_l,
        const float* __restrict__ bias_l, const int* __restrict__ row_ptr,
        float* __restrict__ xi, int residual, float* xs_row) {
    int half = lane >> 5;
    int li = lane & 31;        // channels li*8 .. li*8+7
    int head = li >> 3;        // head
    int start = row_ptr[widx], end = row_ptr[widx + 1];
    float adw = adst[widx * 4 + head];
    float ceh = ce_l[head];
    const uint4* hbv = (const uint4*)hb;

    v2f acc2[4];
    #pragma unroll
    for (int r = 0; r < 4; ++r) { acc2[r].x = 0.f; acc2[r].y = 0.f; }
    float psum = 0.f;

    #define PROC(EI)                                                                  \
        {                                                                             \
            const int2 se = csr[EI];                                                  \
            int s = se.x;                                                             \
            float w = __int_as_float(se.y);                                           \
            const uint4 q = hbv[(unsigned)s * 32u + (unsigned)li];                    \
            float v = asrc[s * 4 + head] + adw + w * ceh;                             \
            v = v > 0.f ? v : 0.2f * v;                                               \
            float p = __expf(v);                                                      \
            psum += p;                                                                \
            v2f pv; pv.x = p; pv.y = p;                                               \
            v2f h0; h0.x = __uint_as_float(q.x << 16); h0.y = __uint_as_float(q.x & 0xffff0000u); \
            v2f h1; h1.x = __uint_as_float(q.y << 16); h1.y = __uint_as_float(q.y & 0xffff0000u); \
            v2f h2; h2.x = __uint_as_float(q.z << 16); h2.y = __uint_as_float(q.z & 0xffff0000u); \
            v2f h3; h3.x = __uint_as_float(q.w << 16); h3.y = __uint_as_float(q.w & 0xffff0000u); \
            acc2[0] += pv * h0;                                                       \
            acc2[1] += pv * h1;                                                       \
            acc2[2] += pv * h2;                                                       \
            acc2[3] += pv * h3;                                                       \
        }

    int ei = start + half;
    for (; ei + 2 < end; ei += 4) {   // 2 edges per half per iter -> 2 gathers in flight
        PROC(ei);
        PROC(ei + 2);
    }
    if (ei < end) PROC(ei);
    #undef PROC

    float acc[8];
    acc[0] = acc2[0].x; acc[1] = acc2[0].y; acc[2] = acc2[1].x; acc[3] = acc2[1].y;
    acc[4] = acc2[2].x; acc[5] = acc2[2].y; acc[6] = acc2[3].x; acc[7] = acc2[3].y;

    psum += __shfl_xor(psum, 32);
    #pragma unroll
    for (int r = 0; r < 8; ++r) acc[r] += __shfl_xor(acc[r], 32);

    float inv = 1.f / (psum + 1e-16f);
    #pragma unroll
    for (int r = 0; r < 8; ++r) acc[r] *= inv;

    #pragma unroll
    for (int r = 0; r < 8; ++r) {
        acc[r] += __shfl_xor(acc[r], 8);
        acc[r] += __shfl_xor(acc[r], 16);
        acc[r] *= 0.25f;
    }

    if (lane < 8) {
        int c0 = lane * 8;
        const float4 b0 = *(const float4*)(bias_l + c0);
        const float4 b1 = *(const float4*)(bias_l + c0 + 4);
        float4 v0, v1;
        v0.x = acc[0] + b0.x; v0.y = acc[1] + b0.y; v0.z = acc[2] + b0.z; v0.w = acc[3] + b0.w;
        v1.x = acc[4] + b1.x; v1.y = acc[5] + b1.y; v1.z = acc[6] + b1.z; v1.w = acc[7] + b1.w;
        float* xo = xi + (size_t)widx * 64 + c0;
        if (residual) {
            const float4 p0 = *(const float4*)xo;
            const float4 p1 = *(const float4*)(xo + 4);
            v0.x += p0.x; v0.y += p0.y; v0.z += p0.z; v0.w += p0.w;
            v1.x += p1.x; v1.y += p1.y; v1.z += p1.z; v1.w += p1.w;
        }
        v0.x = eluf(v0.x); v0.y = eluf(v0.y); v0.z = eluf(v0.z); v0.w = eluf(v0.w);
        v1.x = eluf(v1.x); v1.y = eluf(v1.y); v1.z = eluf(v1.z); v1.w = eluf(v1.w);
        *(float4*)xo = v0;
        *(float4*)(xo + 4) = v1;
        if (WRITE_LDS) {
            *(float4*)(xs_row + c0) = v0;
            *(float4*)(xs_row + c0 + 4) = v1;
        }
    }
}

// ---------------- front dispatch (R23): edge-MLP+hist+mark1 | node_transform<16> ----
// mark1 folded into the MLP branch (it already loads ei_dst per edge): flag1[src]=1
// where dst is a target (d==0 || batch[d]!=batch[d-1]). Deletes 3321 near-empty
// mark1 blocks -> block population 7277 -> 3956 (fill rounds 3.55 -> 1.93).
__global__ void front_kernel(const float* __restrict__ xin, const float* __restrict__ W,
                             const float* __restrict__ a_s, const float* __restrict__ a_d,
                             unsigned short* __restrict__ hb, float* __restrict__ asrc,
                             float* __restrict__ adst,
                             const float* __restrict__ ea,
                             const float* __restrict__ w1, const float* __restrict__ b1,
                             const float* __restrict__ w2, const float* __restrict__ b2,
                             const int* __restrict__ ei_src, const int* __restrict__ ei_dst,
                             int* __restrict__ deg,
                             int2* __restrict__ ewp, float* __restrict__ ew_sum,
                             const int* __restrict__ batch, int* __restrict__ flag1) {
    __shared__ float wt[64 * 8];
    __shared__ float wsum[4];
    __shared__ unsigned short hs[NPB_F * 256];
    const int t = threadIdx.x;
    if (blockIdx.x < MLPB) {
        // ----- edge-MLP + histogram + mark1, 4 edges/thread -----
        if (t < 64) {
            #pragma unroll
            for (int i = 0; i < 5; ++i) wt[t * 8 + i] = w1[i * 64 + t];
            wt[t * 8 + 5] = b1[t];
            wt[t * 8 + 6] = w2[t];
            wt[t * 8 + 7] = 0.f;
        }
        __syncthreads();
        const int e0 = blockIdx.x * 1024 + t;
        float a0[4], a1[4], a2[4], a3[4], a4[4], acc[4];
        #pragma unroll
        for (int m = 0; m < 4; ++m) {
            int e = e0 + 256 * m;
            if (e < NE) {
                a0[m] = ea[e*5+0]; a1[m] = ea[e*5+1]; a2[m] = ea[e*5+2];
                a3[m] = ea[e*5+3]; a4[m] = ea[e*5+4];
            } else {
                a0[m] = a1[m] = a2[m] = a3[m] = a4[m] = 0.f;
            }
            acc[m] = b2[0];
        }
        // histogram atomics + mark1 flags issued before the MLP loop; latency hides under it.
        int pos[4] = {0, 0, 0, 0};
        #pragma unroll
        for (int m = 0; m < 4; ++m) {
            int e = e0 + 256 * m;
            if (e < ET) {
                int d = (e < NE) ? ei_dst[e] : (e - NE);
                int s = (e < NE) ? ei_src[e] : (e - NE);
                pos[m] = atomicAdd(&deg[d], 1);
                bool is_t = (d == 0) || (batch[d] != batch[d - 1]);
                if (is_t) flag1[s] = 1;     // idempotent plain store
            }
        }
        #pragma unroll 4
        for (int j = 0; j < 64; ++j) {
            const float4 lo = *(const float4*)&wt[j * 8];
            const float4 hi = *(const float4*)&wt[j * 8 + 4];
            #pragma unroll
            for (int m = 0; m < 4; ++m) {
                float hj = hi.y + a0[m]*lo.x + a1[m]*lo.y + a2[m]*lo.z + a3[m]*lo.w + a4[m]*hi.x;
                acc[m] += fmaxf(hj, 0.f) * hi.z;
            }
        }
        float vsum = 0.f;
        #pragma unroll
        for (int m = 0; m < 4; ++m) {
            int e = e0 + 256 * m;
            if (e < NE) {
                float val = 1.f / (1.f + __expf(-acc[m]));
                ewp[e] = make_int2(pos[m], __float_as_int(val));
                vsum += val;
            } else if (e < ET) {
                ewp[e] = make_int2(pos[m], 0);
            }
        }
        #pragma unroll
        for (int m = 1; m <= 32; m <<= 1) vsum += __shfl_xor(vsum, m);
        if ((t & 63) == 0) wsum[t >> 6] = vsum;
        __syncthreads();
        if (t == 0) atomicAdd(ew_sum, (wsum[0] + wsum[1]) + (wsum[2] + wsum[3]));
    } else {
        // ----- node_transform, FIN=16, NPB_F=16 (R20-proven body) -----
        const int FIN = 16;
        const int n0 = (blockIdx.x - MLPB) * NPB_F;
        float acc[NPB_F];
        #pragma unroll
        for (int i = 0; i < NPB_F; ++i) acc[i] = 0.f;
        #pragma unroll 4
        for (int k = 0; k < FIN; ++k) {
            float wv = W[k * 256 + t];
            #pragma unroll
            for (int i = 0; i < NPB_F; ++i)
                acc[i] += xin[(size_t)(n0 + i) * FIN + k] * wv;   // uniform address
        }
        int lane = t & 63, head = t >> 6;
        #pragma unroll
        for (int i = 0; i < NPB_F; ++i) hs[i * 256 + t] = f2bf(acc[i]);
        alpha_reduce_store<NPB_F>(acc, a_s[t], a_d[t], lane, head,
                                  [&](int i) { return n0 + i; }, asrc, adst);
        __syncthreads();
        ((uint4*)(hb + (size_t)n0 * 256))[t]       = ((const uint4*)hs)[t];
        ((uint4*)(hb + (size_t)n0 * 256))[t + 256] = ((const uint4*)hs)[t + 256];
    }
}

// ---------------- mark2: flags only, plain stores (needs flag1 complete) ----------------
// 1024-thread blocks: 831 blocks instead of 3321 (launch-round reduction).
__global__ void mark2_kernel(const int* __restrict__ ei_src, const int* __restrict__ ei_dst,
                             const int* __restrict__ flag1, int* __restrict__ flag2) {
    int e = blockIdx.x * 1024 + threadIdx.x;
    if (e >= ET) return;
    int d, s;
    if (e < NE) { d = ei_dst[e]; s = ei_src[e]; } else { d = s = e - NE; }
    if (flag1[d]) flag2[s] = 1;           // idempotent plain store
}

// ---------------- scan phase A (+ ce prep + flag->list compaction, R20-proven) ----------------
__global__ void scan_blocks(const int* __restrict__ deg, int* __restrict__ row_ptr,
                            int* __restrict__ bsum,
                            const float* __restrict__ We, const float* __restrict__ att_e,
                            float* __restrict__ ce,
                            const int* __restrict__ flag1, const int* __restrict__ flag2,
                            int* __restrict__ list1, int* __restrict__ list2,
                            int* __restrict__ cnt1, int* __restrict__ cnt2) {
    __shared__ int sdata[SCAN_B];
    __shared__ int wt1[16], wt2[16];
    __shared__ int base1_s, base2_s;
    int t = threadIdx.x;
    int i = blockIdx.x * SCAN_B + t;
    if (i < 12) {
        int l = i >> 2, h = i & 3;
        float s = 0.f;
        for (int c = 0; c < 64; ++c)
            s += We[l*256 + h*64 + c] * att_e[l*256 + h*64 + c];
        ce[i] = s;
    }
    int v = (i < NN) ? deg[i] : 0;
    sdata[t] = v;
    __syncthreads();
    for (int off = 1; off < SCAN_B; off <<= 1) {
        int tv = (t >= off) ? sdata[t - off] : 0;
        __syncthreads();
        sdata[t] += tv;
        __syncthreads();
    }
    if (i < NN) row_ptr[i + 1] = sdata[t];
    if (t == SCAN_B - 1) bsum[blockIdx.x] = sdata[t];

    // ---- flag compaction (order within lists irrelevant; one atomic/block/list) ----
    int f1 = (i < NN) ? flag1[i] : 0;
    int f2 = (i < NN) ? flag2[i] : 0;
    int lane = t & 63, w = t >> 6;
    unsigned long long b1 = __ballot(f1 != 0);
    unsigned long long b2 = __ballot(f2 != 0);
    unsigned long long below = (lane == 0) ? 0ull : (~0ull >> (64 - lane));
    int r1 = __popcll(b1 & below);
    int r2 = __popcll(b2 & below);
    if (lane == 0) { wt1[w] = __popcll(b1); wt2[w] = __popcll(b2); }
    __syncthreads();
    if (t == 0) {
        int s1 = 0, s2 = 0;
        #pragma unroll
        for (int k = 0; k < 16; ++k) {
            int a = wt1[k]; wt1[k] = s1; s1 += a;
            int b = wt2[k]; wt2[k] = s2; s2 += b;
        }
        base1_s = s1 ? atomicAdd(cnt1, s1) : 0;
        base2_s = s2 ? atomicAdd(cnt2, s2) : 0;
    }
    __syncthreads();
    if (f1) list1[base1_s + wt1[w] + r1] = i;
    if (f2) list2[base2_s + wt2[w] + r2] = i;
}

__global__ void scan_fixup(const int* __restrict__ bsum, int* __restrict__ row_ptr) {
    __shared__ int sboff[64];
    int t = threadIdx.x;   // 256
    if (t < 64) {
        int v = (t < NBLK) ? bsum[t] : 0;
        int inc = v;
        #pragma unroll
        for (int off = 1; off < 64; off <<= 1) {
            int n = __shfl_up(inc, off);
            if (t >= off) inc += n;
        }
        sboff[t] = inc - v;   // exclusive scan
    }
    __syncthreads();
    int i = blockIdx.x * 256 + t;
    if (i < NN) row_ptr[i + 1] += sboff[i >> 10];
    if (i == 0) row_ptr[0] = 0;
}

// cone-only atomic-free scatter: only edges whose dst is in S2 are ever read back.
// 1024-thread blocks (launch-round reduction).
__global__ void scatter_kernel(const int* __restrict__ ei_src, const int* __restrict__ ei_dst,
                               const int* __restrict__ row_ptr, const int2* __restrict__ ewp,
                               const float* __restrict__ ew_sum, const int* __restrict__ flag2,
                               int2* __restrict__ csr) {
    int e = blockIdx.x * 1024 + threadIdx.x;
    if (e >= ET) return;
    int d = (e < NE) ? ei_dst[e] : (e - NE);
    if (!flag2[d]) return;                 // flag2 is L2-resident (200 KB)
    int2 pw = ewp[e];
    int s, wbits;
    if (e < NE) {
        s = ei_src[e];
        wbits = pw.y;
    } else {
        s = d;
        wbits = __float_as_int(ew_sum[0] * (1.f / (float)NE));
    }
    csr[row_ptr[d] + pw.x] = make_int2(s, wbits);
}

// ---------------- list-restricted transform (h = xi @ W, FIN=64) ----------------
__global__ void transform64_list(const int* __restrict__ list, const int* __restrict__ cnt,
                                 const float* __restrict__ xin, const float* __restrict__ W,
                                 const float* __restrict__ a_s, const float* __restrict__ a_d,
                                 unsigned short* __restrict__ hb, float* __restrict__ asrc,
                                 float* __restrict__ adst) {
    const int t = threadIdx.x;
    const int n0 = blockIdx.x * NPB_T;
    const int nv = min(cnt[0], NN);
    if (n0 >= nv) return;
    __shared__ unsigned short hs[NPB_T * 256];
    __shared__ int nls[NPB_T];
    if (t < NPB_T) nls[t] = list[min(n0 + t, nv - 1)];  // clamp -> benign duplicates
    __syncthreads();
    int nreg[NPB_T];
    #pragma unroll
    for (int i = 0; i < NPB_T; ++i) nreg[i] = nls[i];
    float acc[NPB_T];
    #pragma unroll
    for (int i = 0; i < NPB_T; ++i) acc[i] = 0.f;
    #pragma unroll 4
    for (int k = 0; k < 64; ++k) {
        float wv = W[k * 256 + t];
        #pragma unroll
        for (int i = 0; i < NPB_T; ++i)
            acc[i] += xin[(size_t)nreg[i] * 64 + k] * wv;   // wave-uniform address
    }
    int lane = t & 63, head = t >> 6;
    #pragma unroll
    for (int i = 0; i < NPB_T; ++i) hs[i * 256 + t] = f2bf(acc[i]);
    alpha_reduce_store<NPB_T>(acc, a_s[t], a_d[t], lane, head,
                              [&](int i) { return nls[i]; }, asrc, adst);
    __syncthreads();
    int nn = nls[t >> 5];
    ((uint4*)(hb + (size_t)nn * 256))[t & 31] = ((const uint4*)hs)[t];
}

// ---------------- list-restricted aggregation ----------------
__global__ void gat_aggregate_list(const int* __restrict__ list, const int* __restrict__ cnt,
                                   const unsigned short* __restrict__ hb,
                                   const float* __restrict__ asrc, const float* __restrict__ adst,
                                   const int2* __restrict__ csr, const float* __restrict__ ce_l,
                                   const float* __restrict__ bias_l,
                                   const int* __restrict__ row_ptr,
                                   float* __restrict__ xi, int residual) {
    int idx = (blockIdx.x * 256 + threadIdx.x) >> 6;
    int n = min(cnt[0], NN);
    if (idx >= n) return;
    int widx = list[idx];
    int lane = threadIdx.x & 63;
    aggregate_one_node<false>(widx, lane, hb, asrc, adst, csr, ce_l, bias_l, row_ptr,
                              xi, residual, nullptr);
}

// ---------------- fused tail: aggregate(layer 2, 50 targets) + LN + 2-layer MLP ----------
__global__ void readout_fused(const int* __restrict__ batch,
                              const unsigned short* __restrict__ hb,
                              const float* __restrict__ asrc, const float* __restrict__ adst,
                              const int2* __restrict__ csr, const float* __restrict__ ce_l,
                              const float* __restrict__ bias_l, const int* __restrict__ row_ptr,
                              float* __restrict__ xi,
                              const float* __restrict__ ln_g, const float* __restrict__ ln_b,
                              const float* __restrict__ l1w, const float* __restrict__ l1b,
                              const float* __restrict__ l2w, const float* __restrict__ l2b,
                              float* __restrict__ out) {
    int b = blockIdx.x;
    int t = threadIdx.x;   // 64 threads, one wave
    __shared__ int tg_s;
    __shared__ float xs[64];
    if (t == 0) {
        int lo = 0, hi = NN;
        while (lo < hi) {
            int mid = (lo + hi) >> 1;
            if (batch[mid] < b) lo = mid + 1; else hi = mid;
        }
        tg_s = lo;
    }
    __syncthreads();
    int tg = tg_s;
    aggregate_one_node<true>(tg, t, hb, asrc, adst, csr, ce_l, bias_l, row_ptr, xi, 1, xs);
    __syncthreads();
    float x = xs[t];
    float s = x;
    #pragma unroll
    for (int mask = 1; mask <= 32; mask <<= 1) s += __shfl_xor(s, mask);
    float mu = s * (1.f / 64.f);
    float d = x - mu;
    float v = d * d;
    #pragma unroll
    for (int mask = 1; mask <= 32; mask <<= 1) v += __shfl_xor(v, mask);
    float var = v * (1.f / 64.f);
    float xn = d * rsqrtf(var + 1e-5f) * ln_g[t] + ln_b[t];
    __syncthreads();
    xs[t] = xn;
    __syncthreads();
    float acc = l1b[t];
    for (int k = 0; k < 64; ++k) acc += xs[k] * l1w[k * 64 + t];
    acc = eluf(acc);
    __shared__ float st[64];
    st[t] = acc;
    __syncthreads();
    if (t < 3) {
        float o = l2b[t];
        for (int k = 0; k < 64; ++k) o += st[k] * l2w[k * 3 + t];
        out[b * 3 + t] = o;
    }
}

extern "C" void kernel_launch(void* const* d_in, const int* in_sizes, int n_in,
                              void* d_out, int out_size, void* d_ws, size_t ws_size,
                              hipStream_t stream) {
    const float* x        = (const float*)d_in[0];
    const int*   ei       = (const int*)d_in[1];
    const float* ea       = (const float*)d_in[2];
    const int*   batch    = (const int*)d_in[3];
    const float* ee_w1    = (const float*)d_in[4];
    const float* ee_b1    = (const float*)d_in[5];
    const float* ee_w2    = (const float*)d_in[6];
    const float* ee_b2    = (const float*)d_in[7];
    const float* W1       = (const float*)d_in[8];
    const float* Ws       = (const float*)d_in[9];
    const float* att_src  = (const float*)d_in[10];
    const float* att_dst  = (const float*)d_in[11];
    const float* We       = (const float*)d_in[12];
    const float* att_e    = (const float*)d_in[13];
    const float* bias     = (const float*)d_in[14];
    const float* ln_g     = (const float*)d_in[15];
    const float* ln_b     = (const float*)d_in[16];
    const float* lin1_w   = (const float*)d_in[17];
    const float* lin1_b   = (const float*)d_in[18];
    const float* lin2_w   = (const float*)d_in[19];
    const float* lin2_b   = (const float*)d_in[20];
    float* out = (float*)d_out;

    // ---- workspace carve-up (256B aligned) ----
    char* ws = (char*)d_ws;
    size_t off = 0;
    auto alloc = [&](size_t bytes) -> char* {
        char* p = ws + off;
        off += (bytes + 255) & ~(size_t)255;
        return p;
    };
    int2*  ewp     = (int2*)alloc((size_t)ET * 8);
    float* ce      = (float*)alloc(12 * 4);
    unsigned short* hbuf = (unsigned short*)alloc((size_t)NN * 256 * 2);
    float* asrc    = (float*)alloc((size_t)NN * 4 * 4);
    float* adst    = (float*)alloc((size_t)NN * 4 * 4);
    float* xi      = (float*)alloc((size_t)NN * 64 * 4);
    // zeroed region: deg | flag1 | flag2 | misc(ew_sum, cnt1, cnt2)
    int*   deg     = (int*)alloc(((size_t)NN * 3 + 64) * 4);
    int*   flag1   = deg + NN;
    int*   flag2   = deg + 2 * NN;
    float* ew_sum  = (float*)(deg + 3 * NN);
    int*   cnt1    = deg + 3 * NN + 1;
    int*   cnt2    = deg + 3 * NN + 2;
    int*   row_ptr = (int*)alloc((size_t)(NN + 1) * 4);
    int*   bsum    = (int*)alloc(64 * 4);
    int2*  csr     = (int2*)alloc((size_t)ET * 8);
    int*   list1   = (int*)alloc((size_t)NN * 4);
    int*   list2   = (int*)alloc((size_t)NN * 4);
    (void)ws_size; (void)n_in; (void)in_sizes; (void)out_size;

    const int* ei_src = ei;
    const int* ei_dst = ei + NE;

    // 1. front: edge-MLP/hist/mark1 + node_transform<16> (one dispatch, 3956 blocks)
    hipMemsetAsync(deg, 0, ((size_t)NN * 3 + 64) * 4, stream);
    front_kernel<<<MLPB + NTB_F, 256, 0, stream>>>(
        x, W1, att_src + 0 * 256, att_dst + 0 * 256, hbuf, asrc, adst,
        ea, ee_w1, ee_b1, ee_w2, ee_b2, ei_src, ei_dst, deg, ewp, ew_sum,
        batch, flag1);

    // 2. mark2 flags (needs flag1), then scan (+ list compaction), fixup, cone scatter
    mark2_kernel<<<(ET + 1023) / 1024, 1024, 0, stream>>>(ei_src, ei_dst, flag1, flag2);
    scan_blocks<<<NBLK, SCAN_B, 0, stream>>>(deg, row_ptr, bsum, We, att_e, ce,
                                             flag1, flag2, list1, list2, cnt1, cnt2);
    scan_fixup<<<(NN + 255) / 256, 256, 0, stream>>>(bsum, row_ptr);
    scatter_kernel<<<(ET + 1023) / 1024, 1024, 0, stream>>>(ei_src, ei_dst, row_ptr, ewp,
                                                            ew_sum, flag2, csr);

    // 3. GAT layers restricted to the cone (identical arithmetic per node)
    gat_aggregate_list<<<(NN + 3) / 4, 256, 0, stream>>>(list2, cnt2, hbuf, asrc, adst,
                                                         csr, ce + 0 * 4, bias + 0 * 64,
                                                         row_ptr, xi, 0);
    transform64_list<<<NN / NPB_T, 256, 0, stream>>>(list2, cnt2, xi, Ws + 0 * 64 * 256,
                                                     att_src + 1 * 256, att_dst + 1 * 256,
                                                     hbuf, asrc, adst);
    gat_aggregate_list<<<(NN + 3) / 4, 256, 0, stream>>>(list1, cnt1, hbuf, asrc, adst,
                                                         csr, ce + 1 * 4, bias + 1 * 64,
                                                         row_ptr, xi, 1);
    transform64_list<<<NN / NPB_T, 256, 0, stream>>>(list1, cnt1, xi, Ws + 1 * 64 * 256,
                                                     att_src + 2 * 256, att_dst + 2 * 256,
                                                     hbuf, asrc, adst);

    // 4. fused tail: aggregate layer-2 over the 50 targets + LN + MLP
    readout_fused<<<NB, 64, 0, stream>>>(batch, hbuf, asrc, adst, csr, ce + 2 * 4,
                                         bias + 2 * 64, row_ptr, xi,
                                         ln_g, ln_b, lin1_w, lin1_b, lin2_w, lin2_b, out);
}